// Round 1
// baseline (123.459 us; speedup 1.0000x reference)
//
#include <hip/hip_runtime.h>
#include <hip/hip_bf16.h>

typedef float f32x4 __attribute__((ext_vector_type(4)));
typedef short bf16x8 __attribute__((ext_vector_type(8)));

#define ZT 16   // samples per workgroup

// PATHS enumerated l1-major, l2, lo with |l1-l2|<=lo<=l1+l2
constexpr int cL1[15]  = {0,0,0,1,1,1,1,1,1,2,2,2,2,2,2};
constexpr int cL2[15]  = {0,1,2,0,1,1,1,2,2,0,1,1,2,2,2};
constexpr int cLO[15]  = {0,1,2,1,0,1,2,1,2,2,1,2,0,1,2};
constexpr int cCSZ[15] = {1,9,25,9,9,27,45,45,75,25,45,75,25,75,125};
constexpr int cCOFF[15]= {0,1,10,35,44,53,80,125,170,245,270,315,390,415,490}; // total 615
constexpr int cO1[3] = {0,128,512};  // x1 / out irrep block offsets
constexpr int cO2[3] = {0,1,4};      // x2 irrep block offsets
constexpr int cX1O[3]= {0,1,4};      // offset of l-block within per-(z,u) 9-float row

struct CP { const float* p[15]; };

__device__ __forceinline__ ushort f2bf(float f) {
    union { __hip_bfloat16 h; ushort u; } c;
    c.h = __float2bfloat16(f);
    return c.u;
}

// ---- prep kernel: Wb[p][w][u] = bf16(ws[p][u][0][w]) (transpose + convert) ----
__global__ void prep_w(const float* __restrict__ ws, ushort* __restrict__ wb) {
    __shared__ float lds[64 * 132];
    const int p = blockIdx.x;
    const int tid = threadIdx.x;
    const float* src = ws + (size_t)p * 16384;
    ushort* dst = wb + (size_t)p * 16384;
    for (int half = 0; half < 2; ++half) {
        for (int i = tid; i < 8192; i += 256) {          // load 64 u-rows, coalesced
            int u = i >> 7, w = i & 127;
            lds[u * 132 + w] = src[(half * 64 + u) * 128 + w];
        }
        __syncthreads();
        for (int i = tid; i < 8192; i += 256) {          // store transposed, coalesced
            int w = i >> 6, u = i & 63;
            dst[w * 128 + half * 64 + u] = f2bf(lds[u * 132 + w]);
        }
        __syncthreads();
    }
}

// ---- per-path body (fully unrolled via template) ----
template<int P>
__device__ __forceinline__ void path_body(
    int tid, const ushort* __restrict__ Wb, const float* __restrict__ Wsrc, int use_prep,
    const float (&x1r)[8][9],
    float* __restrict__ yl, ushort* __restrict__ Tl,
    const float* __restrict__ cl, const float* __restrict__ x2l,
    f32x4 (&A0)[2][1], f32x4 (&A1)[2][3], f32x4 (&A2)[2][5])
{
    constexpr int l1 = cL1[P], l2 = cL2[P], lo = cLO[P];
    constexpr int d1 = 2*l1+1, d2 = 2*l2+1, dO = 2*lo+1;
    constexpr int span = d1 * dO;
    const int lane = tid & 63, wv = tid >> 6;

    // --- prefetch this path's weight fragments (A operand: rows=w, k=u) ---
    // A and B frags both take 8 CONTIGUOUS k per lane -> identical k-permutation
    // on both operands, so result is independent of HW's internal k-map.
    bf16x8 aP[2][4];
    if (use_prep) {
        const ushort* wp = Wb + P * 16384;
        #pragma unroll
        for (int mt = 0; mt < 2; ++mt)
        #pragma unroll
        for (int ks = 0; ks < 4; ++ks) {
            const int wrow = wv*32 + mt*16 + (lane & 15);
            const int k0   = ks*32 + ((lane >> 4) << 3);
            aP[mt][ks] = *reinterpret_cast<const bf16x8*>(wp + wrow*128 + k0);
        }
    } else {
        const float* wp = Wsrc + P * 16384;   // fallback: strided f32 reads of ws[p][u][0][w]
        #pragma unroll
        for (int mt = 0; mt < 2; ++mt)
        #pragma unroll
        for (int ks = 0; ks < 4; ++ks) {
            const int wrow = wv*32 + mt*16 + (lane & 15);
            const int k0   = ks*32 + ((lane >> 4) << 3);
            bf16x8 v;
            #pragma unroll
            for (int e = 0; e < 8; ++e) v[e] = (short)f2bf(wp[(k0 + e)*128 + wrow]);
            aP[mt][ks] = v;
        }
    }

    // --- y[z,i,k] = sum_j c[i,j,k] * x2[z, O2[l2]+j] ---
    constexpr int ny = ZT * span;
    for (int idx = tid; idx < ny; idx += 256) {
        const int z = idx / span, rem = idx % span;
        const int i = rem / dO, k = rem % dO;
        float s = 0.f;
        #pragma unroll
        for (int j = 0; j < d2; ++j)
            s += cl[cCOFF[P] + (i*d2 + j)*dO + k] * x2l[z*9 + cO2[l2] + j];
        yl[idx] = s;
    }
    __syncthreads();   // y ready; also guarantees prev path's MFMA done reading Tl

    // --- T[col=z*dO+k][u] = bf16( sum_i x1[z,u,i] * y[z,i,k] ) ---
    {
        const int u = tid & 127, zh = tid >> 7;
        #pragma unroll
        for (int r = 0; r < 8; ++r) {
            const int z = 2*r + zh;
            #pragma unroll
            for (int k = 0; k < dO; ++k) {
                float s = 0.f;
                #pragma unroll
                for (int i = 0; i < d1; ++i)
                    s += x1r[r][cX1O[l1] + i] * yl[z*span + i*dO + k];
                Tl[(z*dO + k)*136 + u] = f2bf(s);
            }
        }
    }
    __syncthreads();   // T ready

    // --- MFMA: D[w][col] += sum_u Wt[w][u] * T[u][col] ---
    #pragma unroll
    for (int ks = 0; ks < 4; ++ks) {
        const int k0 = ks*32 + ((lane >> 4) << 3);
        #pragma unroll
        for (int nt = 0; nt < dO; ++nt) {
            const bf16x8 b = *reinterpret_cast<const bf16x8*>(
                Tl + (nt*16 + (lane & 15))*136 + k0);
            if constexpr (lo == 0) {
                A0[0][nt] = __builtin_amdgcn_mfma_f32_16x16x32_bf16(aP[0][ks], b, A0[0][nt], 0,0,0);
                A0[1][nt] = __builtin_amdgcn_mfma_f32_16x16x32_bf16(aP[1][ks], b, A0[1][nt], 0,0,0);
            } else if constexpr (lo == 1) {
                A1[0][nt] = __builtin_amdgcn_mfma_f32_16x16x32_bf16(aP[0][ks], b, A1[0][nt], 0,0,0);
                A1[1][nt] = __builtin_amdgcn_mfma_f32_16x16x32_bf16(aP[1][ks], b, A1[1][nt], 0,0,0);
            } else {
                A2[0][nt] = __builtin_amdgcn_mfma_f32_16x16x32_bf16(aP[0][ks], b, A2[0][nt], 0,0,0);
                A2[1][nt] = __builtin_amdgcn_mfma_f32_16x16x32_bf16(aP[1][ks], b, A2[1][nt], 0,0,0);
            }
        }
    }
}

// ---- epilogue store with 1/sqrt(COUNT) normalization ----
template<int LO, int NT>
__device__ __forceinline__ void store_lo(const f32x4 (&A)[2][NT], float* __restrict__ out,
                                         int z0, int wv, int lane, float scale)
{
    constexpr int dO = 2*LO + 1;
    const int rg = (lane >> 4) << 2, cw = lane & 15;
    #pragma unroll
    for (int mt = 0; mt < 2; ++mt)
    #pragma unroll
    for (int nt = 0; nt < NT; ++nt)
    #pragma unroll
    for (int r = 0; r < 4; ++r) {
        const int row = wv*32 + mt*16 + rg + r;      // w in [0,128)
        const int col = nt*16 + cw;                   // z*dO + k
        const int z = col / dO, k = col % dO;
        out[(size_t)(z0 + z)*1152 + cO1[LO] + row*dO + k] = A[mt][nt][r] * scale;
    }
}

__global__ __launch_bounds__(256, 2)
void tp_main(const float* __restrict__ x1, const float* __restrict__ x2,
             const float* __restrict__ wsrc, const ushort* __restrict__ wb,
             int use_prep, CP cp, float* __restrict__ out)
{
    __shared__ __align__(16) ushort Tl[80 * 136];  // T staging, padded (bank-conflict-free)
    __shared__ float yl[ZT * 25];
    __shared__ float cl[615];
    __shared__ float x2l[ZT * 9];

    const int tid = threadIdx.x;
    const int z0 = blockIdx.x * ZT;

    // preload all CG tensors and the x2 tile
    #pragma unroll
    for (int p = 0; p < 15; ++p)
        for (int i = tid; i < cCSZ[p]; i += 256) cl[cCOFF[p] + i] = cp.p[p][i];
    for (int i = tid; i < ZT * 9; i += 256) x2l[i] = x2[(size_t)z0 * 9 + i];

    // x1 rows held in registers: thread owns (z = 2r + (tid>>7), u = tid&127), r=0..7
    float x1r[8][9];
    {
        const int u = tid & 127, zh = tid >> 7;
        #pragma unroll
        for (int r = 0; r < 8; ++r) {
            const float* b = x1 + (size_t)(z0 + 2*r + zh) * 1152;
            x1r[r][0] = b[u];
            #pragma unroll
            for (int i = 0; i < 3; ++i) x1r[r][1 + i] = b[128 + u*3 + i];
            #pragma unroll
            for (int i = 0; i < 5; ++i) x1r[r][4 + i] = b[512 + u*5 + i];
        }
    }

    f32x4 A0[2][1], A1[2][3], A2[2][5];
    #pragma unroll
    for (int mt = 0; mt < 2; ++mt) {
        A0[mt][0] = (f32x4){0.f, 0.f, 0.f, 0.f};
        #pragma unroll
        for (int nt = 0; nt < 3; ++nt) A1[mt][nt] = (f32x4){0.f, 0.f, 0.f, 0.f};
        #pragma unroll
        for (int nt = 0; nt < 5; ++nt) A2[mt][nt] = (f32x4){0.f, 0.f, 0.f, 0.f};
    }

    __syncthreads();   // cl / x2l ready

    path_body< 0>(tid, wb, wsrc, use_prep, x1r, yl, Tl, cl, x2l, A0, A1, A2);
    path_body< 1>(tid, wb, wsrc, use_prep, x1r, yl, Tl, cl, x2l, A0, A1, A2);
    path_body< 2>(tid, wb, wsrc, use_prep, x1r, yl, Tl, cl, x2l, A0, A1, A2);
    path_body< 3>(tid, wb, wsrc, use_prep, x1r, yl, Tl, cl, x2l, A0, A1, A2);
    path_body< 4>(tid, wb, wsrc, use_prep, x1r, yl, Tl, cl, x2l, A0, A1, A2);
    path_body< 5>(tid, wb, wsrc, use_prep, x1r, yl, Tl, cl, x2l, A0, A1, A2);
    path_body< 6>(tid, wb, wsrc, use_prep, x1r, yl, Tl, cl, x2l, A0, A1, A2);
    path_body< 7>(tid, wb, wsrc, use_prep, x1r, yl, Tl, cl, x2l, A0, A1, A2);
    path_body< 8>(tid, wb, wsrc, use_prep, x1r, yl, Tl, cl, x2l, A0, A1, A2);
    path_body< 9>(tid, wb, wsrc, use_prep, x1r, yl, Tl, cl, x2l, A0, A1, A2);
    path_body<10>(tid, wb, wsrc, use_prep, x1r, yl, Tl, cl, x2l, A0, A1, A2);
    path_body<11>(tid, wb, wsrc, use_prep, x1r, yl, Tl, cl, x2l, A0, A1, A2);
    path_body<12>(tid, wb, wsrc, use_prep, x1r, yl, Tl, cl, x2l, A0, A1, A2);
    path_body<13>(tid, wb, wsrc, use_prep, x1r, yl, Tl, cl, x2l, A0, A1, A2);
    path_body<14>(tid, wb, wsrc, use_prep, x1r, yl, Tl, cl, x2l, A0, A1, A2);

    const int lane = tid & 63, wv = tid >> 6;
    store_lo<0, 1>(A0, out, z0, wv, lane, 0.05103103630798288f);  // 1/sqrt(384)
    store_lo<1, 3>(A1, out, z0, wv, lane, 0.03608439182435161f);  // 1/sqrt(768)
    store_lo<2, 5>(A2, out, z0, wv, lane, 0.03608439182435161f);  // 1/sqrt(768)
}

extern "C" void kernel_launch(void* const* d_in, const int* in_sizes, int n_in,
                              void* d_out, int out_size, void* d_ws, size_t ws_size,
                              hipStream_t stream) {
    const float* x1 = (const float*)d_in[0];
    const float* x2 = (const float*)d_in[1];
    const float* ws = (const float*)d_in[2];
    CP cp;
    for (int p = 0; p < 15; ++p) cp.p[p] = (const float*)d_in[3 + p];
    float* out = (float*)d_out;

    const int N = in_sizes[0] / 1152;         // 16384
    const int use_prep = (ws_size >= (size_t)(15 * 128 * 128 * 2)) ? 1 : 0;

    if (use_prep)
        prep_w<<<15, 256, 0, stream>>>(ws, (ushort*)d_ws);
    tp_main<<<N / ZT, 256, 0, stream>>>(x1, x2, ws, (const ushort*)d_ws,
                                        use_prep, cp, out);
}

// Round 2
// 104.364 us; speedup vs baseline: 1.1830x; 1.1830x over previous
//
#include <hip/hip_runtime.h>
#include <hip/hip_bf16.h>

typedef float f32x4 __attribute__((ext_vector_type(4)));
typedef short bf16x8 __attribute__((ext_vector_type(8)));

#define ZT 16            // samples per workgroup
#define TL_STRIDE 136    // padded u-stride of T tiles (bank-conflict-free b128)
#define TL_BUF (80 * TL_STRIDE)
#define YL_BUF 400       // 16 z * max span 25

// PATHS enumerated l1-major, l2, lo with |l1-l2|<=lo<=l1+l2
constexpr int cL1[15]  = {0,0,0,1,1,1,1,1,1,2,2,2,2,2,2};
constexpr int cL2[15]  = {0,1,2,0,1,1,1,2,2,0,1,1,2,2,2};
constexpr int cLO[15]  = {0,1,2,1,0,1,2,1,2,2,1,2,0,1,2};
constexpr int cCSZ[15] = {1,9,25,9,9,27,45,45,75,25,45,75,25,75,125};
constexpr int cCOFF[15]= {0,1,10,35,44,53,80,125,170,245,270,315,390,415,490}; // total 615
constexpr int cO1[3] = {0,128,512};  // x1 / out irrep block offsets (floats)
constexpr int cO2[3] = {0,1,4};      // x2 irrep block offsets
constexpr int cX1O[3]= {0,1,4};      // offset of l-block within per-(z,u) 9-float row

struct CP { const float* p[15]; };

__device__ __forceinline__ ushort f2bf(float f) {
    union { __hip_bfloat16 h; ushort u; } c;
    c.h = __float2bfloat16(f);
    return c.u;
}

// ---- prep kernel: Wb[p][w][u] = bf16(ws[p][u][0][w]) (transpose + convert) ----
__global__ void prep_w(const float* __restrict__ ws, ushort* __restrict__ wb) {
    __shared__ float lds[64 * 132];
    const int p = blockIdx.x;
    const int tid = threadIdx.x;
    const float* src = ws + (size_t)p * 16384;
    ushort* dst = wb + (size_t)p * 16384;
    for (int half = 0; half < 2; ++half) {
        for (int i = tid; i < 8192; i += 256) {          // load 64 u-rows, coalesced
            int u = i >> 7, w = i & 127;
            lds[u * 132 + w] = src[(half * 64 + u) * 128 + w];
        }
        __syncthreads();
        for (int i = tid; i < 8192; i += 256) {          // store transposed, coalesced
            int w = i >> 6, u = i & 63;
            dst[w * 128 + half * 64 + u] = f2bf(lds[u * 132 + w]);
        }
        __syncthreads();
    }
}

// ---- y[z,i,k] = sum_j c[i,j,k] * x2[z, O2[l2]+j] ----
template<int P>
__device__ __forceinline__ void compute_y(int tid, const float* __restrict__ cl,
                                          const float* __restrict__ x2l,
                                          float* __restrict__ ybuf) {
    constexpr int l2 = cL2[P], lo = cLO[P];
    constexpr int d1 = 2*cL1[P]+1, d2 = 2*l2+1, dO = 2*lo+1;
    constexpr int span = d1 * dO;
    constexpr int ny = ZT * span;
    for (int idx = tid; idx < ny; idx += 256) {
        const int z = idx / span, rem = idx % span;
        const int i = rem / dO, k = rem % dO;
        float s = 0.f;
        #pragma unroll
        for (int j = 0; j < d2; ++j)
            s += cl[cCOFF[P] + (i*d2 + j)*dO + k] * x2l[z*9 + cO2[l2] + j];
        ybuf[idx] = s;
    }
}

// ---- one path iteration: T-phase -> y(P+1) -> barrier -> MFMA.  ONE barrier. ----
template<int P>
__device__ __forceinline__ void path_iter(
    int tid, const ushort* __restrict__ Wb, const float* __restrict__ Wsrc, int use_prep,
    const float (&x1r)[8][9],
    float* __restrict__ yl, ushort* __restrict__ Tl,
    const float* __restrict__ cl, const float* __restrict__ x2l,
    f32x4 (&A0)[2][1], f32x4 (&A1)[2][3], f32x4 (&A2)[2][5])
{
    constexpr int l1 = cL1[P], lo = cLO[P];
    constexpr int d1 = 2*l1+1, dO = 2*lo+1;
    constexpr int span = d1 * dO;
    const int lane = tid & 63, wv = tid >> 6;

    ushort* Tcur = Tl + (P & 1) * TL_BUF;
    const float* ycur = yl + (P & 1) * YL_BUF;

    // --- prefetch this path's weight fragments (A: rows=w, k=u); latency hides
    //     under T-phase + y-phase + barrier ---
    bf16x8 aP[2][4];
    if (use_prep) {
        const ushort* wp = Wb + P * 16384;
        #pragma unroll
        for (int mt = 0; mt < 2; ++mt)
        #pragma unroll
        for (int ks = 0; ks < 4; ++ks) {
            const int wrow = wv*32 + mt*16 + (lane & 15);
            const int k0   = ks*32 + ((lane >> 4) << 3);
            aP[mt][ks] = *reinterpret_cast<const bf16x8*>(wp + wrow*128 + k0);
        }
    } else {
        const float* wp = Wsrc + P * 16384;   // fallback: strided f32 reads of ws[p][u][0][w]
        #pragma unroll
        for (int mt = 0; mt < 2; ++mt)
        #pragma unroll
        for (int ks = 0; ks < 4; ++ks) {
            const int wrow = wv*32 + mt*16 + (lane & 15);
            const int k0   = ks*32 + ((lane >> 4) << 3);
            bf16x8 v;
            #pragma unroll
            for (int e = 0; e < 8; ++e) v[e] = (short)f2bf(wp[(k0 + e)*128 + wrow]);
            aP[mt][ks] = v;
        }
    }

    // --- T[col=z*dO+k][u] = bf16( sum_i x1[z,u,i] * y[z,i,k] ) ---
    {
        const int u = tid & 127, zh = tid >> 7;
        #pragma unroll
        for (int r = 0; r < 8; ++r) {
            const int z = 2*r + zh;
            #pragma unroll
            for (int k = 0; k < dO; ++k) {
                float s = 0.f;
                #pragma unroll
                for (int i = 0; i < d1; ++i)
                    s += x1r[r][cX1O[l1] + i] * ycur[z*span + i*dO + k];
                Tcur[(z*dO + k)*TL_STRIDE + u] = f2bf(s);
            }
        }
    }

    // --- overlap: compute next path's y into the other yl buffer (no hazard:
    //     yl[(P+1)&1] was last read by T(P-1), before the previous barrier) ---
    if constexpr (P < 14)
        compute_y<P + 1>(tid, cl, x2l, yl + ((P + 1) & 1) * YL_BUF);

    __syncthreads();   // T ready; also fences Tl[(P)&1] against T(P+2)'s rewrite

    // --- MFMA: D[w][col] += sum_u Wt[w][u] * T[u][col] ---
    #pragma unroll
    for (int ks = 0; ks < 4; ++ks) {
        const int k0 = ks*32 + ((lane >> 4) << 3);
        #pragma unroll
        for (int nt = 0; nt < dO; ++nt) {
            const bf16x8 b = *reinterpret_cast<const bf16x8*>(
                Tcur + (nt*16 + (lane & 15))*TL_STRIDE + k0);
            if constexpr (lo == 0) {
                A0[0][nt] = __builtin_amdgcn_mfma_f32_16x16x32_bf16(aP[0][ks], b, A0[0][nt], 0,0,0);
                A0[1][nt] = __builtin_amdgcn_mfma_f32_16x16x32_bf16(aP[1][ks], b, A0[1][nt], 0,0,0);
            } else if constexpr (lo == 1) {
                A1[0][nt] = __builtin_amdgcn_mfma_f32_16x16x32_bf16(aP[0][ks], b, A1[0][nt], 0,0,0);
                A1[1][nt] = __builtin_amdgcn_mfma_f32_16x16x32_bf16(aP[1][ks], b, A1[1][nt], 0,0,0);
            } else {
                A2[0][nt] = __builtin_amdgcn_mfma_f32_16x16x32_bf16(aP[0][ks], b, A2[0][nt], 0,0,0);
                A2[1][nt] = __builtin_amdgcn_mfma_f32_16x16x32_bf16(aP[1][ks], b, A2[1][nt], 0,0,0);
            }
        }
    }
}

// ---- epilogue: scale + scatter acc into LDS chunk (4 z), then coalesced store ----
template<int LO, int NT>
__device__ __forceinline__ void stage_lo(const f32x4 (&A)[2][NT], float* __restrict__ stage,
                                         int c, int wv, int rg, int cw, float scale)
{
    constexpr int dO = 2*LO + 1;
    #pragma unroll
    for (int nt = 0; nt < NT; ++nt) {
        const int col = nt*16 + cw;              // z*dO + k
        const int z = col / dO, k = col - z*dO;
        if ((z >> 2) == c) {
            #pragma unroll
            for (int mt = 0; mt < 2; ++mt) {
                const int row = wv*32 + mt*16 + rg;
                float* p = stage + (z & 3)*1152 + cO1[LO] + row*dO + k;
                #pragma unroll
                for (int r = 0; r < 4; ++r) p[r*dO] = A[mt][nt][r] * scale;
            }
        }
    }
}

__global__ __launch_bounds__(256, 2)
void tp_main(const float* __restrict__ x1, const float* __restrict__ x2,
             const float* __restrict__ wsrc, const ushort* __restrict__ wb,
             int use_prep, CP cp, float* __restrict__ out)
{
    __shared__ __align__(16) ushort Tl[2 * TL_BUF];   // 43.5 KB, double-buffered
    __shared__ float yl[2 * YL_BUF];                  // double-buffered y
    __shared__ float cl[615];
    __shared__ float x2l[ZT * 9];

    const int tid = threadIdx.x;
    const int z0 = blockIdx.x * ZT;

    // preload all CG tensors and the x2 tile
    #pragma unroll
    for (int p = 0; p < 15; ++p)
        for (int i = tid; i < cCSZ[p]; i += 256) cl[cCOFF[p] + i] = cp.p[p][i];
    for (int i = tid; i < ZT * 9; i += 256) x2l[i] = x2[(size_t)z0 * 9 + i];

    // x1 rows held in registers: thread owns (z = 2r + (tid>>7), u = tid&127)
    float x1r[8][9];
    {
        const int u = tid & 127, zh = tid >> 7;
        #pragma unroll
        for (int r = 0; r < 8; ++r) {
            const float* b = x1 + (size_t)(z0 + 2*r + zh) * 1152;
            x1r[r][0] = b[u];
            #pragma unroll
            for (int i = 0; i < 3; ++i) x1r[r][1 + i] = b[128 + u*3 + i];
            #pragma unroll
            for (int i = 0; i < 5; ++i) x1r[r][4 + i] = b[512 + u*5 + i];
        }
    }

    f32x4 A0[2][1], A1[2][3], A2[2][5];
    #pragma unroll
    for (int mt = 0; mt < 2; ++mt) {
        A0[mt][0] = (f32x4){0.f, 0.f, 0.f, 0.f};
        #pragma unroll
        for (int nt = 0; nt < 3; ++nt) A1[mt][nt] = (f32x4){0.f, 0.f, 0.f, 0.f};
        #pragma unroll
        for (int nt = 0; nt < 5; ++nt) A2[mt][nt] = (f32x4){0.f, 0.f, 0.f, 0.f};
    }

    __syncthreads();                       // cl / x2l ready
    compute_y<0>(tid, cl, x2l, yl);        // prime y for path 0 into yl[0]
    __syncthreads();                       // y(0) ready

    path_iter< 0>(tid, wb, wsrc, use_prep, x1r, yl, Tl, cl, x2l, A0, A1, A2);
    path_iter< 1>(tid, wb, wsrc, use_prep, x1r, yl, Tl, cl, x2l, A0, A1, A2);
    path_iter< 2>(tid, wb, wsrc, use_prep, x1r, yl, Tl, cl, x2l, A0, A1, A2);
    path_iter< 3>(tid, wb, wsrc, use_prep, x1r, yl, Tl, cl, x2l, A0, A1, A2);
    path_iter< 4>(tid, wb, wsrc, use_prep, x1r, yl, Tl, cl, x2l, A0, A1, A2);
    path_iter< 5>(tid, wb, wsrc, use_prep, x1r, yl, Tl, cl, x2l, A0, A1, A2);
    path_iter< 6>(tid, wb, wsrc, use_prep, x1r, yl, Tl, cl, x2l, A0, A1, A2);
    path_iter< 7>(tid, wb, wsrc, use_prep, x1r, yl, Tl, cl, x2l, A0, A1, A2);
    path_iter< 8>(tid, wb, wsrc, use_prep, x1r, yl, Tl, cl, x2l, A0, A1, A2);
    path_iter< 9>(tid, wb, wsrc, use_prep, x1r, yl, Tl, cl, x2l, A0, A1, A2);
    path_iter<10>(tid, wb, wsrc, use_prep, x1r, yl, Tl, cl, x2l, A0, A1, A2);
    path_iter<11>(tid, wb, wsrc, use_prep, x1r, yl, Tl, cl, x2l, A0, A1, A2);
    path_iter<12>(tid, wb, wsrc, use_prep, x1r, yl, Tl, cl, x2l, A0, A1, A2);
    path_iter<13>(tid, wb, wsrc, use_prep, x1r, yl, Tl, cl, x2l, A0, A1, A2);
    path_iter<14>(tid, wb, wsrc, use_prep, x1r, yl, Tl, cl, x2l, A0, A1, A2);

    // ---- coalesced epilogue: 4 chunks of 4 z, staged through LDS ----
    const int lane = tid & 63, wv = tid >> 6;
    const int rg = (lane >> 4) << 2, cw = lane & 15;
    float* stage = (float*)Tl;             // 18.4 KB needed, 43.5 KB available
    #pragma unroll
    for (int c = 0; c < 4; ++c) {
        __syncthreads();                   // stage region free (MFMA/prev-reads done)
        stage_lo<0, 1>(A0, stage, c, wv, rg, cw, 0.05103103630798288f);  // 1/sqrt(384)
        stage_lo<1, 3>(A1, stage, c, wv, rg, cw, 0.03608439182435161f);  // 1/sqrt(768)
        stage_lo<2, 5>(A2, stage, c, wv, rg, cw, 0.03608439182435161f);  // 1/sqrt(768)
        __syncthreads();                   // chunk staged
        float4* dst = (float4*)(out + (size_t)(z0 + 4*c) * 1152);
        const float4* src = (const float4*)stage;
        #pragma unroll
        for (int it = 0; it < 5; ++it) {
            const int idx = it * 256 + tid;      // float4 index, 1152 total
            if (idx < 1152) dst[idx] = src[idx];
        }
    }
}

extern "C" void kernel_launch(void* const* d_in, const int* in_sizes, int n_in,
                              void* d_out, int out_size, void* d_ws, size_t ws_size,
                              hipStream_t stream) {
    const float* x1 = (const float*)d_in[0];
    const float* x2 = (const float*)d_in[1];
    const float* ws = (const float*)d_in[2];
    CP cp;
    for (int p = 0; p < 15; ++p) cp.p[p] = (const float*)d_in[3 + p];
    float* out = (float*)d_out;

    const int N = in_sizes[0] / 1152;         // 16384
    const int use_prep = (ws_size >= (size_t)(15 * 128 * 128 * 2)) ? 1 : 0;

    if (use_prep)
        prep_w<<<15, 256, 0, stream>>>(ws, (ushort*)d_ws);
    tp_main<<<N / ZT, 256, 0, stream>>>(x1, x2, ws, (const ushort*)d_ws,
                                        use_prep, cp, out);
}

// Round 3
// 93.515 us; speedup vs baseline: 1.3202x; 1.1160x over previous
//
#include <hip/hip_runtime.h>
#include <hip/hip_bf16.h>

typedef float f32x4 __attribute__((ext_vector_type(4)));
typedef short bf16x8 __attribute__((ext_vector_type(8)));

#define ZT 16            // samples per workgroup
#define TL_STRIDE 136    // padded u-stride of T tiles (16B-aligned rows)
#define TL_BUF (80 * TL_STRIDE)
#define YL_BUF 448       // 16 z * max padded span 28

// PATHS enumerated l1-major, l2, lo with |l1-l2|<=lo<=l1+l2
constexpr int cL1[15]  = {0,0,0,1,1,1,1,1,1,2,2,2,2,2,2};
constexpr int cL2[15]  = {0,1,2,0,1,1,1,2,2,0,1,1,2,2,2};
constexpr int cLO[15]  = {0,1,2,1,0,1,2,1,2,2,1,2,0,1,2};
constexpr int cCSZ[15] = {1,9,25,9,9,27,45,45,75,25,45,75,25,75,125};
constexpr int cCOFF[15]= {0,1,10,35,44,53,80,125,170,245,270,315,390,415,490}; // total 615
constexpr int cO1[3] = {0,128,512};  // x1 / out irrep block offsets (floats)
constexpr int cO2[3] = {0,1,4};      // x2 irrep block offsets
constexpr int cX1O[3]= {0,1,4};      // offset of l-block within per-(z,u) 9-float row

struct CP { const float* p[15]; };

__device__ __forceinline__ ushort f2bf(float f) {
    union { __hip_bfloat16 h; ushort u; } c;
    c.h = __float2bfloat16(f);
    return c.u;
}

// ---- prep kernel: Wb[p][w][u] = bf16(ws[p][u][0][w]) (transpose + convert) ----
__global__ void prep_w(const float* __restrict__ ws, ushort* __restrict__ wb) {
    __shared__ float lds[64 * 132];
    const int p = blockIdx.x;
    const int tid = threadIdx.x;
    const float* src = ws + (size_t)p * 16384;
    ushort* dst = wb + (size_t)p * 16384;
    for (int half = 0; half < 2; ++half) {
        for (int i = tid; i < 8192; i += 256) {          // load 64 u-rows, coalesced
            int u = i >> 7, w = i & 127;
            lds[u * 132 + w] = src[(half * 64 + u) * 128 + w];
        }
        __syncthreads();
        for (int i = tid; i < 8192; i += 256) {          // store transposed, coalesced
            int w = i >> 6, u = i & 63;
            dst[w * 128 + half * 64 + u] = f2bf(lds[u * 132 + w]);
        }
        __syncthreads();
    }
}

// ---- y[z,i,k] = sum_j c[i,j,k] * x2[z, O2[l2]+j], padded per-z stride ----
template<int P>
__device__ __forceinline__ void compute_y(int tid, const float* __restrict__ cl,
                                          const float* __restrict__ x2l,
                                          float* __restrict__ ybuf) {
    constexpr int l2 = cL2[P], lo = cLO[P];
    constexpr int d1 = 2*cL1[P]+1, d2 = 2*l2+1, dO = 2*lo+1;
    constexpr int span = d1 * dO;
    constexpr int span_pad = (span + 3) & ~3;
    constexpr int ny = ZT * span_pad;
    for (int idx = tid; idx < ny; idx += 256) {
        const int z = idx / span_pad, rem = idx - z * span_pad;
        float s = 0.f;
        if (rem < span) {
            const int i = rem / dO, k = rem - i * dO;
            #pragma unroll
            for (int j = 0; j < d2; ++j)
                s += cl[cCOFF[P] + (i*d2 + j)*dO + k] * x2l[z*9 + cO2[l2] + j];
        }
        ybuf[idx] = s;   // pad slots get 0; never consumed
    }
}

// ---- one path iteration: T-phase -> y(P+1) -> barrier -> MFMA.  ONE barrier. ----
template<int P>
__device__ __forceinline__ void path_iter(
    int tid, const ushort* __restrict__ Wb, const float* __restrict__ Wsrc, int use_prep,
    const float (&x1r)[4][2][9],
    float* __restrict__ yl, ushort* __restrict__ Tl,
    const float* __restrict__ cl, const float* __restrict__ x2l,
    f32x4 (&A0)[2][1], f32x4 (&A1)[2][3], f32x4 (&A2)[2][5])
{
    constexpr int l1 = cL1[P], lo = cLO[P];
    constexpr int d1 = 2*l1+1, dO = 2*lo+1;
    constexpr int span = d1 * dO;
    constexpr int span_pad = (span + 3) & ~3;
    const int lane = tid & 63, wv = tid >> 6;

    ushort* Tcur = Tl + (P & 1) * TL_BUF;
    const float* ycur = yl + (P & 1) * YL_BUF;

    // --- prefetch this path's weight fragments (A: rows=w, k=u); latency hides
    //     under T-phase + y-phase + barrier ---
    bf16x8 aP[2][4];
    if (use_prep) {
        const ushort* wp = Wb + P * 16384;
        #pragma unroll
        for (int mt = 0; mt < 2; ++mt)
        #pragma unroll
        for (int ks = 0; ks < 4; ++ks) {
            const int wrow = wv*32 + mt*16 + (lane & 15);
            const int k0   = ks*32 + ((lane >> 4) << 3);
            aP[mt][ks] = *reinterpret_cast<const bf16x8*>(wp + wrow*128 + k0);
        }
    } else {
        const float* wp = Wsrc + P * 16384;   // fallback: strided f32 reads of ws[p][u][0][w]
        #pragma unroll
        for (int mt = 0; mt < 2; ++mt)
        #pragma unroll
        for (int ks = 0; ks < 4; ++ks) {
            const int wrow = wv*32 + mt*16 + (lane & 15);
            const int k0   = ks*32 + ((lane >> 4) << 3);
            bf16x8 v;
            #pragma unroll
            for (int e = 0; e < 8; ++e) v[e] = (short)f2bf(wp[(k0 + e)*128 + wrow]);
            aP[mt][ks] = v;
        }
    }

    // --- T-phase: thread owns u-pair (2*lane, 2*lane+1), z in {4*wv..4*wv+3}.
    //     y rows loaded once per z as b128 wave-uniform broadcasts into regs;
    //     T written as packed bf16x2 b32 (conflict-free: 64 consecutive words) ---
    {
        const int u0 = 2 * lane;
        #pragma unroll
        for (int r = 0; r < 4; ++r) {
            const int z = wv * 4 + r;
            f32x4 yv[span_pad / 4];
            #pragma unroll
            for (int j = 0; j < span_pad / 4; ++j)
                yv[j] = *reinterpret_cast<const f32x4*>(ycur + z * span_pad + 4 * j);
            #pragma unroll
            for (int k = 0; k < dO; ++k) {
                float s0 = 0.f, s1 = 0.f;
                #pragma unroll
                for (int i = 0; i < d1; ++i) {
                    constexpr int base = 0;  (void)base;
                    const int yi = i * dO + k;              // compile-time after unroll
                    const float yf = yv[yi >> 2][yi & 3];
                    s0 += x1r[r][0][cX1O[l1] + i] * yf;
                    s1 += x1r[r][1][cX1O[l1] + i] * yf;
                }
                union { uint u32; ushort h[2]; } pk;
                pk.h[0] = f2bf(s0);
                pk.h[1] = f2bf(s1);
                *reinterpret_cast<uint*>(Tcur + (z * dO + k) * TL_STRIDE + u0) = pk.u32;
            }
        }
    }

    // --- overlap: compute next path's y into the other yl buffer (no hazard:
    //     yl[(P+1)&1] was last read by T(P-1), before the previous barrier) ---
    if constexpr (P < 14)
        compute_y<P + 1>(tid, cl, x2l, yl + ((P + 1) & 1) * YL_BUF);

    __syncthreads();   // T ready; also fences Tl[(P)&1] against T(P+2)'s rewrite

    // --- MFMA: D[w][col] += sum_u Wt[w][u] * T[u][col] ---
    #pragma unroll
    for (int ks = 0; ks < 4; ++ks) {
        const int k0 = ks*32 + ((lane >> 4) << 3);
        #pragma unroll
        for (int nt = 0; nt < dO; ++nt) {
            const bf16x8 b = *reinterpret_cast<const bf16x8*>(
                Tcur + (nt*16 + (lane & 15))*TL_STRIDE + k0);
            if constexpr (lo == 0) {
                A0[0][nt] = __builtin_amdgcn_mfma_f32_16x16x32_bf16(aP[0][ks], b, A0[0][nt], 0,0,0);
                A0[1][nt] = __builtin_amdgcn_mfma_f32_16x16x32_bf16(aP[1][ks], b, A0[1][nt], 0,0,0);
            } else if constexpr (lo == 1) {
                A1[0][nt] = __builtin_amdgcn_mfma_f32_16x16x32_bf16(aP[0][ks], b, A1[0][nt], 0,0,0);
                A1[1][nt] = __builtin_amdgcn_mfma_f32_16x16x32_bf16(aP[1][ks], b, A1[1][nt], 0,0,0);
            } else {
                A2[0][nt] = __builtin_amdgcn_mfma_f32_16x16x32_bf16(aP[0][ks], b, A2[0][nt], 0,0,0);
                A2[1][nt] = __builtin_amdgcn_mfma_f32_16x16x32_bf16(aP[1][ks], b, A2[1][nt], 0,0,0);
            }
        }
    }
}

// ---- epilogue: scale + scatter acc into LDS chunk (4 z), then coalesced store ----
template<int LO, int NT>
__device__ __forceinline__ void stage_lo(const f32x4 (&A)[2][NT], float* __restrict__ stage,
                                         int c, int wv, int rg, int cw, float scale)
{
    constexpr int dO = 2*LO + 1;
    #pragma unroll
    for (int nt = 0; nt < NT; ++nt) {
        const int col = nt*16 + cw;              // z*dO + k
        const int z = col / dO, k = col - z*dO;
        if ((z >> 2) == c) {
            #pragma unroll
            for (int mt = 0; mt < 2; ++mt) {
                const int row = wv*32 + mt*16 + rg;
                float* p = stage + (z & 3)*1152 + cO1[LO] + row*dO + k;
                #pragma unroll
                for (int r = 0; r < 4; ++r) p[r*dO] = A[mt][nt][r] * scale;
            }
        }
    }
}

__global__ __launch_bounds__(256, 2)
void tp_main(const float* __restrict__ x1, const float* __restrict__ x2,
             const float* __restrict__ wsrc, const ushort* __restrict__ wb,
             int use_prep, CP cp, float* __restrict__ out)
{
    __shared__ __align__(16) ushort Tl[2 * TL_BUF];   // 43.5 KB, double-buffered
    __shared__ __align__(16) float yl[2 * YL_BUF];    // double-buffered padded y
    __shared__ float cl[615];
    __shared__ float x2l[ZT * 9];

    const int tid = threadIdx.x;
    const int z0 = blockIdx.x * ZT;
    const int lane = tid & 63, wv = tid >> 6;

    // preload all CG tensors and the x2 tile
    #pragma unroll
    for (int p = 0; p < 15; ++p)
        for (int i = tid; i < cCSZ[p]; i += 256) cl[cCOFF[p] + i] = cp.p[p][i];
    for (int i = tid; i < ZT * 9; i += 256) x2l[i] = x2[(size_t)z0 * 9 + i];

    // x1 in registers: thread owns u-pair (2*lane, 2*lane+1) for z = 4*wv + r
    float x1r[4][2][9];
    #pragma unroll
    for (int r = 0; r < 4; ++r) {
        const float* b = x1 + (size_t)(z0 + wv*4 + r) * 1152;
        {   // l=0 block: x1[z, u]          (float2 at 2*lane)
            const float2 t = *reinterpret_cast<const float2*>(b + 2*lane);
            x1r[r][0][0] = t.x; x1r[r][1][0] = t.y;
        }
        {   // l=1 block: x1[z, 128 + u*3 + i]
            float f6[6];
            #pragma unroll
            for (int j = 0; j < 3; ++j) {
                const float2 t = *reinterpret_cast<const float2*>(b + 128 + 6*lane + 2*j);
                f6[2*j] = t.x; f6[2*j + 1] = t.y;
            }
            #pragma unroll
            for (int i = 0; i < 3; ++i) { x1r[r][0][1+i] = f6[i]; x1r[r][1][1+i] = f6[3+i]; }
        }
        {   // l=2 block: x1[z, 512 + u*5 + i]
            float f10[10];
            #pragma unroll
            for (int j = 0; j < 5; ++j) {
                const float2 t = *reinterpret_cast<const float2*>(b + 512 + 10*lane + 2*j);
                f10[2*j] = t.x; f10[2*j + 1] = t.y;
            }
            #pragma unroll
            for (int i = 0; i < 5; ++i) { x1r[r][0][4+i] = f10[i]; x1r[r][1][4+i] = f10[5+i]; }
        }
    }

    f32x4 A0[2][1], A1[2][3], A2[2][5];
    #pragma unroll
    for (int mt = 0; mt < 2; ++mt) {
        A0[mt][0] = (f32x4){0.f, 0.f, 0.f, 0.f};
        #pragma unroll
        for (int nt = 0; nt < 3; ++nt) A1[mt][nt] = (f32x4){0.f, 0.f, 0.f, 0.f};
        #pragma unroll
        for (int nt = 0; nt < 5; ++nt) A2[mt][nt] = (f32x4){0.f, 0.f, 0.f, 0.f};
    }

    __syncthreads();                       // cl / x2l ready
    compute_y<0>(tid, cl, x2l, yl);        // prime y for path 0 into yl[0]
    __syncthreads();                       // y(0) ready

    path_iter< 0>(tid, wb, wsrc, use_prep, x1r, yl, Tl, cl, x2l, A0, A1, A2);
    path_iter< 1>(tid, wb, wsrc, use_prep, x1r, yl, Tl, cl, x2l, A0, A1, A2);
    path_iter< 2>(tid, wb, wsrc, use_prep, x1r, yl, Tl, cl, x2l, A0, A1, A2);
    path_iter< 3>(tid, wb, wsrc, use_prep, x1r, yl, Tl, cl, x2l, A0, A1, A2);
    path_iter< 4>(tid, wb, wsrc, use_prep, x1r, yl, Tl, cl, x2l, A0, A1, A2);
    path_iter< 5>(tid, wb, wsrc, use_prep, x1r, yl, Tl, cl, x2l, A0, A1, A2);
    path_iter< 6>(tid, wb, wsrc, use_prep, x1r, yl, Tl, cl, x2l, A0, A1, A2);
    path_iter< 7>(tid, wb, wsrc, use_prep, x1r, yl, Tl, cl, x2l, A0, A1, A2);
    path_iter< 8>(tid, wb, wsrc, use_prep, x1r, yl, Tl, cl, x2l, A0, A1, A2);
    path_iter< 9>(tid, wb, wsrc, use_prep, x1r, yl, Tl, cl, x2l, A0, A1, A2);
    path_iter<10>(tid, wb, wsrc, use_prep, x1r, yl, Tl, cl, x2l, A0, A1, A2);
    path_iter<11>(tid, wb, wsrc, use_prep, x1r, yl, Tl, cl, x2l, A0, A1, A2);
    path_iter<12>(tid, wb, wsrc, use_prep, x1r, yl, Tl, cl, x2l, A0, A1, A2);
    path_iter<13>(tid, wb, wsrc, use_prep, x1r, yl, Tl, cl, x2l, A0, A1, A2);
    path_iter<14>(tid, wb, wsrc, use_prep, x1r, yl, Tl, cl, x2l, A0, A1, A2);

    // ---- coalesced epilogue: 4 chunks of 4 z, staged through LDS ----
    const int rg = (lane >> 4) << 2, cw = lane & 15;
    float* stage = (float*)Tl;             // 18.4 KB needed, 43.5 KB available
    #pragma unroll
    for (int c = 0; c < 4; ++c) {
        __syncthreads();                   // stage region free (MFMA/prev-reads done)
        stage_lo<0, 1>(A0, stage, c, wv, rg, cw, 0.05103103630798288f);  // 1/sqrt(384)
        stage_lo<1, 3>(A1, stage, c, wv, rg, cw, 0.03608439182435161f);  // 1/sqrt(768)
        stage_lo<2, 5>(A2, stage, c, wv, rg, cw, 0.03608439182435161f);  // 1/sqrt(768)
        __syncthreads();                   // chunk staged
        float4* dst = (float4*)(out + (size_t)(z0 + 4*c) * 1152);
        const float4* src = (const float4*)stage;
        #pragma unroll
        for (int it = 0; it < 5; ++it) {
            const int idx = it * 256 + tid;      // float4 index, 1152 total
            if (idx < 1152) dst[idx] = src[idx];
        }
    }
}

extern "C" void kernel_launch(void* const* d_in, const int* in_sizes, int n_in,
                              void* d_out, int out_size, void* d_ws, size_t ws_size,
                              hipStream_t stream) {
    const float* x1 = (const float*)d_in[0];
    const float* x2 = (const float*)d_in[1];
    const float* ws = (const float*)d_in[2];
    CP cp;
    for (int p = 0; p < 15; ++p) cp.p[p] = (const float*)d_in[3 + p];
    float* out = (float*)d_out;

    const int N = in_sizes[0] / 1152;         // 16384
    const int use_prep = (ws_size >= (size_t)(15 * 128 * 128 * 2)) ? 1 : 0;

    if (use_prep)
        prep_w<<<15, 256, 0, stream>>>(ws, (ushort*)d_ws);
    tp_main<<<N / ZT, 256, 0, stream>>>(x1, x2, ws, (const ushort*)d_ws,
                                        use_prep, cp, out);
}